// Round 1
// baseline (50.646 us; speedup 1.0000x reference)
//
#include <hip/hip_runtime.h>
#include <math.h>

#define B 32
#define C 4
#define CF 5

// ---------------- kernel 0: evo weight matrix w = exp(-2*y)/(rowsum+eps) ----
__global__ __launch_bounds__(1024) void k_w(const float* __restrict__ yevo,
                                            float* __restrict__ w) {
    __shared__ float e[1024];
    __shared__ float rs[32];
    int t = threadIdx.x;                  // t = i*32 + j
    float ev = expf(-2.0f * yevo[t]);
    e[t] = ev;
    __syncthreads();
    if (t < 32) {
        float s = 0.f;
        #pragma unroll
        for (int j = 0; j < 32; ++j) s += e[t * 32 + j];
        rs[t] = s + 1e-8f;
    }
    __syncthreads();
    w[t] = ev / rs[t >> 5];
}

// ---------------- kernel 1: one wave per sequence position l -----------------
// Stages the 32 batch rows at position l into LDS, then computes
// CE + R2 + masked pairwise-JS contributions; wave-reduces 5 partials.
__global__ __launch_bounds__(64) void k_main(const float* __restrict__ logits,
                                             const float* __restrict__ prob,
                                             const float* __restrict__ y_true,
                                             const float* __restrict__ w,
                                             float* __restrict__ partials,
                                             int L) {
    const int l = blockIdx.x;
    const int lane = threadIdx.x;

    __shared__ float sp[32][4];      // clamped probs
    __shared__ float splogp[32];     // sum p*log p
    __shared__ float salt[32];       // y_true[1]+y_true[2]+y_true[3]
    __shared__ float spalt[32];      // prob[1]+prob[2]+prob[3] (raw)
    __shared__ int   slbl[32];

    float ce = 0.f, valid = 0.f;

    if (lane < 32) {
        const int b = lane;
        const float* yt = y_true + ((size_t)b * L + l) * CF;
        float y0 = yt[0], y1 = yt[1], y2 = yt[2], y3 = yt[3], y4 = yt[4];
        int lbl = 0; float best = y0;
        if (y1 > best) { best = y1; lbl = 1; }
        if (y2 > best) { best = y2; lbl = 2; }
        if (y3 > best) { best = y3; lbl = 3; }
        if (y4 > best) { best = y4; lbl = 4; }
        slbl[b] = lbl;
        salt[b] = y1 + y2 + y3;

        const float* pr = prob + ((size_t)b * L + l) * C;
        float p0 = pr[0], p1 = pr[1], p2 = pr[2], p3 = pr[3];
        spalt[b] = p1 + p2 + p3;
        float q0 = fmaxf(p0, 1e-7f), q1 = fmaxf(p1, 1e-7f);
        float q2 = fmaxf(p2, 1e-7f), q3 = fmaxf(p3, 1e-7f);
        sp[b][0] = q0; sp[b][1] = q1; sp[b][2] = q2; sp[b][3] = q3;
        splogp[b] = q0 * logf(q0) + q1 * logf(q1) + q2 * logf(q2) + q3 * logf(q3);

        if (lbl != 4) {
            const float* lg = logits + ((size_t)b * L + l) * C;
            float a0 = lg[0], a1 = lg[1], a2 = lg[2], a3 = lg[3];
            float mx = fmaxf(fmaxf(a0, a1), fmaxf(a2, a3));
            float se = expf(a0 - mx) + expf(a1 - mx) + expf(a2 - mx) + expf(a3 - mx);
            float lse = mx + logf(se);
            float al = (lbl == 0) ? a0 : (lbl == 1) ? a1 : (lbl == 2) ? a2 : a3;
            ce = lse - al;     // nll
            valid = 1.f;
        }
    }
    __syncthreads();

    // ---- R2 over 8 groups of 4 ----
    float r2s = 0.f, tv = 0.f;
    if (lane < 8) {
        const int g = lane;
        float nmc = 0.f, altc = 0.f, ps = 0.f;
        int lb[4];
        #pragma unroll
        for (int m = 0; m < 4; ++m) {
            int b = g * 4 + m;
            lb[m] = slbl[b];
            nmc += (lb[m] != 4) ? 1.f : 0.f;
            altc += salt[b];
            ps += spalt[b];
        }
        float af = altc / fmaxf(nmc, 1.f);
        float pred = 0.25f * ps;
        #pragma unroll
        for (int m = 0; m < 4; ++m) {
            bool miss = (lb[m] == 4);
            float taf = miss ? 0.5f : af;
            bool edge = (taf == 0.f) || (taf == 1.f);
            float denom = fmaxf(taf * (1.f - taf), 0.01f);
            float d = pred - taf;
            float r2 = d * d / denom;
            if (edge || miss) r2 = 0.f;
            float gr2 = -r2;
            r2s += gr2;
            if (nmc > 0.f && gr2 != 0.f) tv += 1.f;
        }
    }

    // ---- evo: masked pairwise JS, weighted, scalar accumulation ----
    float evo = 0.f;
    #pragma unroll 4
    for (int kk = 0; kk < 16; ++kk) {
        int k = kk * 64 + lane;         // 0..1023 ordered pairs
        int i = k >> 5, j = k & 31;
        int li = slbl[i];
        if (i != j && li == slbl[j] && li != 4) {
            float mlogm = 0.f;
            #pragma unroll
            for (int c = 0; c < 4; ++c) {
                float m = 0.5f * (sp[i][c] + sp[j][c]);
                mlogm += m * logf(m);
            }
            float js = 0.5f * (splogp[i] + splogp[j]) - mlogm;
            evo += w[i * 32 + j] * js;
        }
    }

    // ---- wave (64-lane) reduction of the 5 partials ----
    #pragma unroll
    for (int off = 32; off; off >>= 1) {
        ce    += __shfl_xor(ce, off);
        valid += __shfl_xor(valid, off);
        r2s   += __shfl_xor(r2s, off);
        tv    += __shfl_xor(tv, off);
        evo   += __shfl_xor(evo, off);
    }
    if (lane == 0) {
        const int nb = gridDim.x;
        partials[0 * nb + blockIdx.x] = ce;
        partials[1 * nb + blockIdx.x] = valid;
        partials[2 * nb + blockIdx.x] = r2s;
        partials[3 * nb + blockIdx.x] = tv;
        partials[4 * nb + blockIdx.x] = evo;
    }
}

// ---------------- kernel 2: final reduction + epilogue -----------------------
__global__ __launch_bounds__(256) void k_final(const float* __restrict__ partials,
                                               float* __restrict__ out, int nb) {
    __shared__ float red[256];
    __shared__ float acc[5];
    const int t = threadIdx.x;
    for (int a = 0; a < 5; ++a) {
        float s = 0.f;
        for (int idx = t; idx < nb; idx += 256) s += partials[a * nb + idx];
        red[t] = s;
        __syncthreads();
        for (int off = 128; off; off >>= 1) {
            if (t < off) red[t] += red[t + off];
            __syncthreads();
        }
        if (t == 0) acc[a] = red[0];
        __syncthreads();
    }
    if (t == 0) {
        float ce_sum = acc[0], valid = acc[1], r2_sum = acc[2],
              tv = acc[3], evo_sum = acc[4];
        float ce_loss = (valid > 0.f) ? (ce_sum / fmaxf(valid, 1.f)) : ce_sum;
        float r2_loss = 0.1f * ((tv > 0.f) ? (r2_sum / fmaxf(tv, 1.f)) : r2_sum);
        float evo = 10.f * (evo_sum / 32.f);
        if (!isfinite(evo)) evo = 0.f;
        out[0] = 1000.f * (ce_loss + r2_loss + evo);
    }
}

extern "C" void kernel_launch(void* const* d_in, const int* in_sizes, int n_in,
                              void* d_out, int out_size, void* d_ws, size_t ws_size,
                              hipStream_t stream) {
    const float* logits = (const float*)d_in[0];
    const float* prob   = (const float*)d_in[1];
    const float* y_true = (const float*)d_in[2];
    const float* yevo   = (const float*)d_in[3];
    float* out = (float*)d_out;

    const int L = in_sizes[0] / (B * C);   // 4096

    float* w        = (float*)d_ws;        // 1024 floats
    float* partials = w + 1024;            // 5*L floats

    k_w<<<1, 1024, 0, stream>>>(yevo, w);
    k_main<<<L, 64, 0, stream>>>(logits, prob, y_true, w, partials, L);
    k_final<<<1, 256, 0, stream>>>(partials, out, L);
}

// Round 2
// 30.163 us; speedup vs baseline: 1.6791x; 1.6791x over previous
//
#include <hip/hip_runtime.h>
#include <math.h>

#define B 32
#define C 4
#define CF 5
#define NPAIR 496   // 32*31/2 unordered pairs, diagonal excluded (JS(i,i)==0)

// ---------------- kernel 0: evo weights, folded symmetric pair table --------
// w = exp(-2*y)/(rowsum+eps);  wsum[t] = w[i][j]+w[j][i] for the t-th (i<j)
// pair; pairij[t] = (i<<8)|j.
__global__ __launch_bounds__(1024) void k_w(const float* __restrict__ yevo,
                                            float* __restrict__ wsum,
                                            int* __restrict__ pairij) {
    __shared__ float e[1024];
    __shared__ float rs[32];
    const int t = threadIdx.x;
    const int i = t >> 5, j = t & 31;
    float ev = __expf(-2.0f * yevo[t]);
    e[t] = ev;
    __syncthreads();
    if (t < 32) {
        float s = 0.f;
        #pragma unroll
        for (int c = 0; c < 32; ++c) s += e[t * 32 + c];
        rs[t] = s + 1e-8f;
    }
    __syncthreads();
    float wv = ev / rs[i];
    e[t] = wv;               // old e fully consumed before this barrier pair
    __syncthreads();
    if (i < j) {
        int idx = i * (63 - i) / 2 + (j - i - 1);   // compact upper-tri rank
        wsum[idx] = e[i * 32 + j] + e[j * 32 + i];
        pairij[idx] = (i << 8) | j;
    }
}

// ---------------- kernel 1: one 64-lane wave per sequence position l --------
__global__ __launch_bounds__(64) void k_main(const float* __restrict__ logits,
                                             const float* __restrict__ prob,
                                             const float* __restrict__ y_true,
                                             const float* __restrict__ wsum,
                                             const int* __restrict__ pairij,
                                             float* __restrict__ partials,
                                             int L) {
    const int l = blockIdx.x;
    const int lane = threadIdx.x;

    __shared__ float4 sp4[32];       // clamped probs
    __shared__ float splogp[32];     // sum p*log p
    __shared__ float salt[32];       // y_true[1..3] sum
    __shared__ float spalt[32];      // prob[1..3] sum (raw)
    __shared__ int   slbl[32];

    float ce = 0.f, valid = 0.f;

    if (lane < 32) {
        const int b = lane;
        const float* yt = y_true + ((size_t)b * L + l) * CF;
        float y0 = yt[0], y1 = yt[1], y2 = yt[2], y3 = yt[3], y4 = yt[4];
        int lbl = 0; float best = y0;
        if (y1 > best) { best = y1; lbl = 1; }
        if (y2 > best) { best = y2; lbl = 2; }
        if (y3 > best) { best = y3; lbl = 3; }
        if (y4 > best) { best = y4; lbl = 4; }
        slbl[b] = lbl;
        salt[b] = y1 + y2 + y3;

        const float4 pv = *(const float4*)(prob + ((size_t)b * L + l) * C);
        spalt[b] = pv.y + pv.z + pv.w;
        float q0 = fmaxf(pv.x, 1e-7f), q1 = fmaxf(pv.y, 1e-7f);
        float q2 = fmaxf(pv.z, 1e-7f), q3 = fmaxf(pv.w, 1e-7f);
        sp4[b] = make_float4(q0, q1, q2, q3);
        splogp[b] = q0 * __logf(q0) + q1 * __logf(q1)
                  + q2 * __logf(q2) + q3 * __logf(q3);

        if (lbl != 4) {
            const float4 av = *(const float4*)(logits + ((size_t)b * L + l) * C);
            float mx = fmaxf(fmaxf(av.x, av.y), fmaxf(av.z, av.w));
            float se = __expf(av.x - mx) + __expf(av.y - mx)
                     + __expf(av.z - mx) + __expf(av.w - mx);
            float lse = mx + __logf(se);
            float al = (lbl == 0) ? av.x : (lbl == 1) ? av.y
                     : (lbl == 2) ? av.z : av.w;
            ce = lse - al;
            valid = 1.f;
        }
    }
    __syncthreads();

    // ---- R2 over 8 groups of 4 ----
    float r2s = 0.f, tv = 0.f;
    if (lane < 8) {
        const int g = lane;
        float nmc = 0.f, altc = 0.f, ps = 0.f;
        int lb[4];
        #pragma unroll
        for (int m = 0; m < 4; ++m) {
            int b = g * 4 + m;
            lb[m] = slbl[b];
            nmc += (lb[m] != 4) ? 1.f : 0.f;
            altc += salt[b];
            ps += spalt[b];
        }
        float af = altc / fmaxf(nmc, 1.f);
        float pred = 0.25f * ps;
        #pragma unroll
        for (int m = 0; m < 4; ++m) {
            bool miss = (lb[m] == 4);
            float taf = miss ? 0.5f : af;
            bool edge = (taf == 0.f) || (taf == 1.f);
            float denom = fmaxf(taf * (1.f - taf), 0.01f);
            float d = pred - taf;
            float r2 = d * d / denom;
            if (edge || miss) r2 = 0.f;
            r2s -= r2;
            if (nmc > 0.f && r2 != 0.f) tv += 1.f;
        }
    }

    // ---- evo: 496 unordered pairs, folded weights, fast log ----
    float evo = 0.f;
    #pragma unroll
    for (int it = 0; it < 8; ++it) {
        int s = it * 64 + lane;
        if (s < NPAIR) {
            int pk = pairij[s];
            int i = pk >> 8, j = pk & 255;
            int li = slbl[i];
            if (li == slbl[j] && li != 4) {
                float4 a = sp4[i], bq = sp4[j];
                float m0 = 0.5f * (a.x + bq.x), m1 = 0.5f * (a.y + bq.y);
                float m2 = 0.5f * (a.z + bq.z), m3 = 0.5f * (a.w + bq.w);
                float mlogm = m0 * __logf(m0) + m1 * __logf(m1)
                            + m2 * __logf(m2) + m3 * __logf(m3);
                float js = 0.5f * (splogp[i] + splogp[j]) - mlogm;
                evo += wsum[s] * js;
            }
        }
    }

    // ---- wave reduction of the 5 partials ----
    #pragma unroll
    for (int off = 32; off; off >>= 1) {
        ce    += __shfl_xor(ce, off);
        valid += __shfl_xor(valid, off);
        r2s   += __shfl_xor(r2s, off);
        tv    += __shfl_xor(tv, off);
        evo   += __shfl_xor(evo, off);
    }
    if (lane == 0) {
        partials[0 * L + l] = ce;
        partials[1 * L + l] = valid;
        partials[2 * L + l] = r2s;
        partials[3 * L + l] = tv;
        partials[4 * L + l] = evo;
    }
}

// ---------------- kernel 2: single-pass final reduction + epilogue ----------
__global__ __launch_bounds__(256) void k_final(const float* __restrict__ partials,
                                               float* __restrict__ out, int nb) {
    __shared__ float acc[4][5];
    const int t = threadIdx.x;
    float s0 = 0.f, s1 = 0.f, s2 = 0.f, s3 = 0.f, s4 = 0.f;
    for (int idx = t; idx < nb; idx += 256) {
        s0 += partials[0 * nb + idx];
        s1 += partials[1 * nb + idx];
        s2 += partials[2 * nb + idx];
        s3 += partials[3 * nb + idx];
        s4 += partials[4 * nb + idx];
    }
    #pragma unroll
    for (int off = 32; off; off >>= 1) {
        s0 += __shfl_xor(s0, off);
        s1 += __shfl_xor(s1, off);
        s2 += __shfl_xor(s2, off);
        s3 += __shfl_xor(s3, off);
        s4 += __shfl_xor(s4, off);
    }
    const int w = t >> 6;
    if ((t & 63) == 0) {
        acc[w][0] = s0; acc[w][1] = s1; acc[w][2] = s2;
        acc[w][3] = s3; acc[w][4] = s4;
    }
    __syncthreads();
    if (t == 0) {
        float ce_sum = acc[0][0] + acc[1][0] + acc[2][0] + acc[3][0];
        float valid  = acc[0][1] + acc[1][1] + acc[2][1] + acc[3][1];
        float r2_sum = acc[0][2] + acc[1][2] + acc[2][2] + acc[3][2];
        float tvs    = acc[0][3] + acc[1][3] + acc[2][3] + acc[3][3];
        float evo_s  = acc[0][4] + acc[1][4] + acc[2][4] + acc[3][4];
        float ce_loss = (valid > 0.f) ? (ce_sum / fmaxf(valid, 1.f)) : ce_sum;
        float r2_loss = 0.1f * ((tvs > 0.f) ? (r2_sum / fmaxf(tvs, 1.f)) : r2_sum);
        float evo = 10.f * (evo_s / 32.f);
        if (!isfinite(evo)) evo = 0.f;
        out[0] = 1000.f * (ce_loss + r2_loss + evo);
    }
}

extern "C" void kernel_launch(void* const* d_in, const int* in_sizes, int n_in,
                              void* d_out, int out_size, void* d_ws, size_t ws_size,
                              hipStream_t stream) {
    const float* logits = (const float*)d_in[0];
    const float* prob   = (const float*)d_in[1];
    const float* y_true = (const float*)d_in[2];
    const float* yevo   = (const float*)d_in[3];
    float* out = (float*)d_out;

    const int L = in_sizes[0] / (B * C);   // 4096

    float* wsum     = (float*)d_ws;            // 512 floats (496 used)
    int*   pairij   = (int*)d_ws + 512;        // 512 ints  (496 used)
    float* partials = (float*)d_ws + 1024;     // 5*L floats

    k_w<<<1, 1024, 0, stream>>>(yevo, wsum, pairij);
    k_main<<<L, 64, 0, stream>>>(logits, prob, y_true, wsum, pairij, partials, L);
    k_final<<<1, 256, 0, stream>>>(partials, out, L);
}